// Round 7
// baseline (60.458 us; speedup 1.0000x reference)
//
#include <hip/hip_runtime.h>

#define OUT_F 11008
#define IN_F  4096
#define KSTEP 256              // k per step: lane*4, int4 / ds_read_b128
#define NSTEP (IN_F / KSTEP)   // 16 steps

// Block = 256 threads = 4 waves, all on ONE batch-half (4 batches).
// Wave i handles rows [row0+4i, row0+4i+4) x 4 batches x full K.
// Grid = 688 row-blocks x 2 batch-halves = 1376 blocks.
//
// KEY MECHANISM (R6): x lives in LDS (staged once, 64 KB -> 2 blocks/CU);
// in the K-loop x reads are ds_read_b128 (lgkmcnt) while weights are the
// ONLY vmcnt traffic. This decouples the two latency domains: the FMA's
// x-wait (lgkmcnt(4)) no longer force-retires in-flight weight loads, so
// the register triple-buffered w stream keeps depth-2 (~2 steps ~ 800 cyc
// issue-to-use), covering HBM latency. In R4 the shared vmcnt queue let
// the 1-step-old x wait drain the w prefetch to depth-1 (~350 cyc).
// zero-point folded: out = s*(dot - zp*rowsum(x_b)) + bias, rowsum in-loop.
// NOTE: plain __launch_bounds__(256) — ",N" variants forced spills (R3).
__global__ __launch_bounds__(256) void qlinear_kernel(
        const float* __restrict__ in, const int* __restrict__ qw,
        const int* __restrict__ zp, const float* __restrict__ scale,
        const float* __restrict__ bias, float* __restrict__ out) {
    const int lane   = threadIdx.x & 63;
    const int wave   = threadIdx.x >> 6;     // 0..3
    const int bh     = blockIdx.x & 1;       // batch half: batches bh*4..bh*4+3
    const int rowblk = blockIdx.x >> 1;      // 0..687
    const int row0   = rowblk * 16 + wave * 4;
    const int l4     = lane * 4;

    __shared__ float x_lds[4 * IN_F];        // 64 KB: this half's 4 batch rows

    // ---- stage x into LDS: wave b copies batch row (bh*4+b), coalesced ----
    {
        const float* src = in + (size_t)(bh * 4 + wave) * IN_F;
        float* dst = &x_lds[wave * IN_F];
        #pragma unroll
        for (int i = 0; i < IN_F / 256; ++i) {       // 16 x 1KB per wave
            const int o = i * 256 + l4;
            *reinterpret_cast<float4*>(dst + o) =
                *reinterpret_cast<const float4*>(src + o);
        }
    }
    __syncthreads();   // only barrier; K-loop below is barrier-free

    const int* qp = qw + (size_t)row0 * IN_F + l4;

    float acc[4][4];
    float asum[4];
    #pragma unroll
    for (int r = 0; r < 4; ++r)
        #pragma unroll
        for (int b = 0; b < 4; ++b) acc[r][b] = 0.f;
    #pragma unroll
    for (int b = 0; b < 4; ++b) asum[b] = 0.f;

    int4   wv[3][4];   // weight triple buffer: depth-2 prefetch on vmcnt
    float4 xv[2][4];   // x double buffer from LDS: depth-1 on lgkmcnt

    // prologue: w(0), w(1) in flight; x(0) from LDS
    #pragma unroll
    for (int r = 0; r < 4; ++r)
        wv[0][r] = *reinterpret_cast<const int4*>(qp + r * IN_F);
    #pragma unroll
    for (int r = 0; r < 4; ++r)
        wv[1][r] = *reinterpret_cast<const int4*>(qp + r * IN_F + KSTEP);
    #pragma unroll
    for (int b = 0; b < 4; ++b)
        xv[0][b] = *reinterpret_cast<const float4*>(&x_lds[b * IN_F + l4]);

    #pragma unroll
    for (int t = 0; t < NSTEP; ++t) {
        // w(t+2): depth-2 weight prefetch (vmcnt only)
        if (t + 2 < NSTEP) {
            #pragma unroll
            for (int r = 0; r < 4; ++r)
                wv[(t + 2) % 3][r] =
                    *reinterpret_cast<const int4*>(qp + r * IN_F + (t + 2) * KSTEP);
        }
        // x(t+1): next step's activations from LDS (lgkmcnt only)
        if (t + 1 < NSTEP) {
            #pragma unroll
            for (int b = 0; b < 4; ++b)
                xv[(t + 1) & 1][b] = *reinterpret_cast<const float4*>(
                    &x_lds[b * IN_F + (t + 1) * KSTEP + l4]);
        }

        // FMA(t): consumes w issued 2 steps ago, x issued 1 step ago
        float f[4][4];
        #pragma unroll
        for (int r = 0; r < 4; ++r) {
            f[r][0] = (float)wv[t % 3][r].x;
            f[r][1] = (float)wv[t % 3][r].y;
            f[r][2] = (float)wv[t % 3][r].z;
            f[r][3] = (float)wv[t % 3][r].w;
        }
        #pragma unroll
        for (int b = 0; b < 4; ++b) {
            const float4 x = xv[t & 1][b];
            asum[b] += (x.x + x.y) + (x.z + x.w);
            #pragma unroll
            for (int r = 0; r < 4; ++r)
                acc[r][b] += f[r][0] * x.x + f[r][1] * x.y
                           + f[r][2] * x.z + f[r][3] * x.w;
        }
    }

    // --- cross-lane reduce of 16 accumulators (register-halving tree):
    // 4 levels -> lane holds index (lane&15) summed within its 16-lane group;
    // + xor16 + xor32 -> full 64-lane sum on lanes 0..15.
    float v[16];
    #pragma unroll
    for (int r = 0; r < 4; ++r)
        #pragma unroll
        for (int b = 0; b < 4; ++b) v[r * 4 + b] = acc[r][b];

    #pragma unroll
    for (int k = 0; k < 4; ++k) {
        const bool hi = (lane >> k) & 1;
        const int  nn = 16 >> k;
        #pragma unroll
        for (int i = 0; i < 16; ++i) {
            if (i < nn / 2) {
                float keep = hi ? v[2 * i + 1] : v[2 * i];
                float send = hi ? v[2 * i]     : v[2 * i + 1];
                v[i] = keep + __shfl_xor(send, 1 << k);
            }
        }
    }
    float total = v[0];
    total += __shfl_xor(total, 16);
    total += __shfl_xor(total, 32);

    // --- reduce 4 row-sum accumulators -> rowsum of batch (lane&3)
    float s4[4];
    #pragma unroll
    for (int b = 0; b < 4; ++b) s4[b] = asum[b];
    #pragma unroll
    for (int k = 0; k < 2; ++k) {
        const bool hi = (lane >> k) & 1;
        const int  nn = 4 >> k;
        #pragma unroll
        for (int i = 0; i < 4; ++i) {
            if (i < nn / 2) {
                float keep = hi ? s4[2 * i + 1] : s4[2 * i];
                float send = hi ? s4[2 * i]     : s4[2 * i + 1];
                s4[i] = keep + __shfl_xor(send, 1 << k);
            }
        }
    }
    float S = s4[0];
    S += __shfl_xor(S, 4);
    S += __shfl_xor(S, 8);
    S += __shfl_xor(S, 16);
    S += __shfl_xor(S, 32);   // full rowsum of batch (lane&3)

    if (lane < 16) {
        const int r  = lane >> 2;         // 0..3
        const int b  = lane & 3;          // 0..3
        const int o  = row0 + r;
        const int bg = bh * 4 + b;
        out[(size_t)bg * OUT_F + o] =
            scale[o] * (total - (float)zp[o] * S) + bias[o];
    }
}

extern "C" void kernel_launch(void* const* d_in, const int* in_sizes, int n_in,
                              void* d_out, int out_size, void* d_ws, size_t ws_size,
                              hipStream_t stream) {
    const float* in    = (const float*)d_in[0];
    const int*   qw    = (const int*)  d_in[1];
    const int*   zp    = (const int*)  d_in[2];
    const float* scale = (const float*)d_in[3];
    const float* bias  = (const float*)d_in[4];
    float*       out   = (float*)d_out;

    const int blocks = (OUT_F / 16) * 2;   // 1376: 688 row-blocks x 2 halves
    qlinear_kernel<<<blocks, 256, 0, stream>>>(in, qw, zp, scale, bias, out);
}

// Round 8
// 43.277 us; speedup vs baseline: 1.3970x; 1.3970x over previous
//
#include <hip/hip_runtime.h>

#define OUT_F 11008
#define IN_F  4096
#define KSTEP 256              // k per step: lane*4, int4/float4 16B loads
#define NSTEP (IN_F / KSTEP)   // 16 steps

// R7: one wave per block. Wave = 4 output rows x 8 batches x FULL K.
// Grid = 2752 single-wave blocks (~10.75 waves/CU) -> the command processor
// back-fills CUs wave-by-wave: no generation quantization, no drain bubble,
// no barrier, no LDS. Pipeline discipline identical to R4 (best, 40.5us):
// per step, issue x(t) [8x float4, L2-resident] then w(t+1) [4x int4,
// depth-1 prefetch]; the FMA's x-wait (vmcnt(4)) retires w(t) but keeps
// w(t+1) in flight. 16B loads only (R5 isolated 8B loads as a 18% loss).
// zero-point folded: out = s*(dot - zp*rowsum(x_b)) + bias, rowsum in-loop.
// NOTE: plain __launch_bounds__ — ",N" variants forced spills (R3).
__global__ __launch_bounds__(64) void qlinear_kernel(
        const float* __restrict__ in, const int* __restrict__ qw,
        const int* __restrict__ zp, const float* __restrict__ scale,
        const float* __restrict__ bias, float* __restrict__ out) {
    const int lane = threadIdx.x;            // 0..63
    const int row0 = blockIdx.x * 4;
    const int l4   = lane * 4;

    const int*   qp = qw + (size_t)row0 * IN_F + l4;
    const float* xp = in + l4;

    float acc[4][8];
    float asum[8];
    #pragma unroll
    for (int r = 0; r < 4; ++r)
        #pragma unroll
        for (int b = 0; b < 8; ++b) acc[r][b] = 0.f;
    #pragma unroll
    for (int b = 0; b < 8; ++b) asum[b] = 0.f;

    int4 wbuf[2][4];
    #pragma unroll
    for (int r = 0; r < 4; ++r)
        wbuf[0][r] = *reinterpret_cast<const int4*>(qp + r * IN_F);

    #pragma unroll
    for (int t = 0; t < NSTEP; ++t) {        // fully unrolled -> static idx
        const int c = t & 1, n = c ^ 1;

        // x(t): issued first so the FMA's x-wait (vmcnt(4)) keeps w(t+1)
        // in flight while draining only w(t).
        float4 x[8];
        #pragma unroll
        for (int b = 0; b < 8; ++b)
            x[b] = *reinterpret_cast<const float4*>(xp + b * IN_F + t * KSTEP);

        // w(t+1): depth-1 prefetch of the weight stream
        if (t + 1 < NSTEP) {
            #pragma unroll
            for (int r = 0; r < 4; ++r)
                wbuf[n][r] = *reinterpret_cast<const int4*>(qp + r * IN_F + (t + 1) * KSTEP);
        }

        float f[4][4];
        #pragma unroll
        for (int r = 0; r < 4; ++r) {
            f[r][0] = (float)wbuf[c][r].x;
            f[r][1] = (float)wbuf[c][r].y;
            f[r][2] = (float)wbuf[c][r].z;
            f[r][3] = (float)wbuf[c][r].w;
        }
        #pragma unroll
        for (int b = 0; b < 8; ++b) {
            const float4 xv = x[b];
            asum[b] += (xv.x + xv.y) + (xv.z + xv.w);
            #pragma unroll
            for (int r = 0; r < 4; ++r)
                acc[r][b] += f[r][0] * xv.x + f[r][1] * xv.y
                           + f[r][2] * xv.z + f[r][3] * xv.w;
        }
    }

    // --- cross-lane reduce of 32 accumulators (register-halving tree):
    // 5 levels -> lane l holds index (l&31) summed over its 32-lane half;
    // +xor32 -> full 64-lane sum on lanes 0..31. index = r*8 + b.
    float v[32];
    #pragma unroll
    for (int r = 0; r < 4; ++r)
        #pragma unroll
        for (int b = 0; b < 8; ++b) v[r * 8 + b] = acc[r][b];

    #pragma unroll
    for (int k = 0; k < 5; ++k) {
        const bool hi = (lane >> k) & 1;
        const int  nn = 32 >> k;
        #pragma unroll
        for (int i = 0; i < 32; ++i) {
            if (i < nn / 2) {
                float keep = hi ? v[2 * i + 1] : v[2 * i];
                float send = hi ? v[2 * i]     : v[2 * i + 1];
                v[i] = keep + __shfl_xor(send, 1 << k);
            }
        }
    }
    const float total = v[0] + __shfl_xor(v[0], 32);

    // --- reduce 8 row-sum accumulators -> rowsum of batch (lane&7)
    float s8[8];
    #pragma unroll
    for (int b = 0; b < 8; ++b) s8[b] = asum[b];
    #pragma unroll
    for (int k = 0; k < 3; ++k) {
        const bool hi = (lane >> k) & 1;
        const int  nn = 8 >> k;
        #pragma unroll
        for (int i = 0; i < 8; ++i) {
            if (i < nn / 2) {
                float keep = hi ? s8[2 * i + 1] : s8[2 * i];
                float send = hi ? s8[2 * i]     : s8[2 * i + 1];
                s8[i] = keep + __shfl_xor(send, 1 << k);
            }
        }
    }
    float S = s8[0];
    S += __shfl_xor(S, 8);
    S += __shfl_xor(S, 16);
    S += __shfl_xor(S, 32);   // full rowsum of batch (lane&7)

    if (lane < 32) {
        const int r = lane >> 3;          // 0..3
        const int b = lane & 7;           // 0..7
        const int o = row0 + r;
        out[(size_t)b * OUT_F + o] =
            scale[o] * (total - (float)zp[o] * S) + bias[o];
    }
}

extern "C" void kernel_launch(void* const* d_in, const int* in_sizes, int n_in,
                              void* d_out, int out_size, void* d_ws, size_t ws_size,
                              hipStream_t stream) {
    const float* in    = (const float*)d_in[0];
    const int*   qw    = (const int*)  d_in[1];
    const int*   zp    = (const int*)  d_in[2];
    const float* scale = (const float*)d_in[3];
    const float* bias  = (const float*)d_in[4];
    float*       out   = (float*)d_out;

    const int blocks = OUT_F / 4;   // 2752 single-wave blocks
    qlinear_kernel<<<blocks, 64, 0, stream>>>(in, qw, zp, scale, bias, out);
}

// Round 9
// 40.927 us; speedup vs baseline: 1.4772x; 1.0574x over previous
//
#include <hip/hip_runtime.h>

#define OUT_F 11008
#define IN_F  4096
#define KSTEP 256              // k per step: lane*4, int4/float4 16B loads
#define NSTEP (IN_F / KSTEP)   // 16 steps

// R8 = R7 + depth-2 weight prefetch (the single change).
// One wave per block: wave = 4 output rows x 8 batches x FULL K.
// Grid = 2752 single-wave blocks (~10.75 waves/CU, 2.69/SIMD) -> VGPR up to
// ~168 is free (3 waves/SIMD >= grid supply).
// Pipeline: per step t issue x(t+1) [8x float4, L2] then w(t+2) [4x int4,
// HBM/L3], then FMA(t). The FMA's wait retires through x(t) (vmcnt(16)),
// always leaving {w(t+1), x(t+1), w(t+2)} in flight: weight issue-to-use
// ~= 2 full steps (~1200+ cyc), covering under-load HBM latency that R7's
// depth-1 (~600 cyc) did not. R7 evidence: per-wave latency ~3500 cyc/step
// vs ~340 cyc VALU -> ~90% stall, supply BW irrelevant (L3-resident replays
// equally slow).
// zero-point folded: out = s*(dot - zp*rowsum(x_b)) + bias, rowsum in-loop.
// NOTE: plain __launch_bounds__ — ",N" variants forced spills (R3).
__global__ __launch_bounds__(64) void qlinear_kernel(
        const float* __restrict__ in, const int* __restrict__ qw,
        const int* __restrict__ zp, const float* __restrict__ scale,
        const float* __restrict__ bias, float* __restrict__ out) {
    const int lane = threadIdx.x;            // 0..63
    const int row0 = blockIdx.x * 4;
    const int l4   = lane * 4;

    const int*   qp = qw + (size_t)row0 * IN_F + l4;
    const float* xp = in + l4;

    float acc[4][8];
    float asum[8];
    #pragma unroll
    for (int r = 0; r < 4; ++r)
        #pragma unroll
        for (int b = 0; b < 8; ++b) acc[r][b] = 0.f;
    #pragma unroll
    for (int b = 0; b < 8; ++b) asum[b] = 0.f;

    int4   wv[3][4];   // weight triple buffer: depth-2 prefetch
    float4 xv[2][8];   // x double buffer: depth-1

#define W_LOAD(BUF, S) do {                                                   \
        _Pragma("unroll")                                                     \
        for (int r = 0; r < 4; ++r)                                           \
            BUF[r] = *reinterpret_cast<const int4*>(qp + r * IN_F + (S) * KSTEP); \
    } while (0)
#define X_LOAD(BUF, S) do {                                                   \
        _Pragma("unroll")                                                     \
        for (int b = 0; b < 8; ++b)                                           \
            BUF[b] = *reinterpret_cast<const float4*>(xp + b * IN_F + (S) * KSTEP); \
    } while (0)

    // prologue: w(0) oldest, then x(0), then w(1)
    W_LOAD(wv[0], 0);
    X_LOAD(xv[0], 0);
    W_LOAD(wv[1], 1);

    #pragma unroll
    for (int t = 0; t < NSTEP; ++t) {        // fully unrolled -> static idx
        // x(t+1) first (so the next FMA's x-wait leaves newer w in flight)
        if (t + 1 < NSTEP) X_LOAD(xv[(t + 1) & 1], t + 1);
        // w(t+2): depth-2 weight prefetch
        if (t + 2 < NSTEP) W_LOAD(wv[(t + 2) % 3], t + 2);

        // FMA(t): w issued 2 steps ago, x issued 1 step ago
        float f[4][4];
        #pragma unroll
        for (int r = 0; r < 4; ++r) {
            f[r][0] = (float)wv[t % 3][r].x;
            f[r][1] = (float)wv[t % 3][r].y;
            f[r][2] = (float)wv[t % 3][r].z;
            f[r][3] = (float)wv[t % 3][r].w;
        }
        #pragma unroll
        for (int b = 0; b < 8; ++b) {
            const float4 x = xv[t & 1][b];
            asum[b] += (x.x + x.y) + (x.z + x.w);
            #pragma unroll
            for (int r = 0; r < 4; ++r)
                acc[r][b] += f[r][0] * x.x + f[r][1] * x.y
                           + f[r][2] * x.z + f[r][3] * x.w;
        }
    }

#undef W_LOAD
#undef X_LOAD

    // --- cross-lane reduce of 32 accumulators (register-halving tree):
    // 5 levels -> lane l holds index (l&31) summed over its 32-lane half;
    // +xor32 -> full 64-lane sum on lanes 0..31. index = r*8 + b.
    float v[32];
    #pragma unroll
    for (int r = 0; r < 4; ++r)
        #pragma unroll
        for (int b = 0; b < 8; ++b) v[r * 8 + b] = acc[r][b];

    #pragma unroll
    for (int k = 0; k < 5; ++k) {
        const bool hi = (lane >> k) & 1;
        const int  nn = 32 >> k;
        #pragma unroll
        for (int i = 0; i < 32; ++i) {
            if (i < nn / 2) {
                float keep = hi ? v[2 * i + 1] : v[2 * i];
                float send = hi ? v[2 * i]     : v[2 * i + 1];
                v[i] = keep + __shfl_xor(send, 1 << k);
            }
        }
    }
    const float total = v[0] + __shfl_xor(v[0], 32);

    // --- reduce 8 row-sum accumulators -> rowsum of batch (lane&7)
    float s8[8];
    #pragma unroll
    for (int b = 0; b < 8; ++b) s8[b] = asum[b];
    #pragma unroll
    for (int k = 0; k < 3; ++k) {
        const bool hi = (lane >> k) & 1;
        const int  nn = 8 >> k;
        #pragma unroll
        for (int i = 0; i < 8; ++i) {
            if (i < nn / 2) {
                float keep = hi ? s8[2 * i + 1] : s8[2 * i];
                float send = hi ? s8[2 * i]     : s8[2 * i + 1];
                s8[i] = keep + __shfl_xor(send, 1 << k);
            }
        }
    }
    float S = s8[0];
    S += __shfl_xor(S, 8);
    S += __shfl_xor(S, 16);
    S += __shfl_xor(S, 32);   // full rowsum of batch (lane&7)

    if (lane < 32) {
        const int r = lane >> 3;          // 0..3
        const int b = lane & 7;           // 0..7
        const int o = row0 + r;
        out[(size_t)b * OUT_F + o] =
            scale[o] * (total - (float)zp[o] * S) + bias[o];
    }
}

extern "C" void kernel_launch(void* const* d_in, const int* in_sizes, int n_in,
                              void* d_out, int out_size, void* d_ws, size_t ws_size,
                              hipStream_t stream) {
    const float* in    = (const float*)d_in[0];
    const int*   qw    = (const int*)  d_in[1];
    const int*   zp    = (const int*)  d_in[2];
    const float* scale = (const float*)d_in[3];
    const float* bias  = (const float*)d_in[4];
    float*       out   = (float*)d_out;

    const int blocks = OUT_F / 4;   // 2752 single-wave blocks
    qlinear_kernel<<<blocks, 64, 0, stream>>>(in, qw, zp, scale, bias, out);
}